// Round 1
// baseline (1009.975 us; speedup 1.0000x reference)
//
#include <hip/hip_runtime.h>

typedef unsigned short u16;
typedef unsigned int u32;
typedef __bf16 bf16_t;
typedef bf16_t bf16x8 __attribute__((ext_vector_type(8)));
typedef float f32x4 __attribute__((ext_vector_type(4)));

__device__ __forceinline__ u16 f2bf(float f){
  u32 u = __float_as_uint(f);
  u32 r = (u + 0x7fffu + ((u >> 16) & 1u)) >> 16;
  return (u16)r;
}
__device__ __forceinline__ float bf2f(u16 h){
  return __uint_as_float(((u32)h) << 16);
}
__device__ __forceinline__ bf16x8 ldfrag(const u16* p){
  union { uint4 u; bf16x8 b; } x;
  x.u = *(const uint4*)p;
  return x.b;
}

// ---------------- CSR build ----------------

__global__ void detect_kernel(const int* __restrict__ ei, int* __restrict__ flag){
  // if edge_index is int64, the high words (odd int32 slots) of row 0 are all 0
  if (threadIdx.x == 0 && blockIdx.x == 0){
    int orv = 0;
    for (int i = 0; i < 200; i++) orv |= ei[2*i + 1];
    *flag = (orv == 0) ? 1 : 0;
  }
}

__global__ void init_kernel(int* __restrict__ cnt, int* __restrict__ fillpos, int n){
  int i = blockIdx.x * blockDim.x + threadIdx.x;
  if (i < n){ cnt[i] = 1; fillpos[i] = 1; } // slot 0 = self loop
}

__global__ void count_edges(const int* __restrict__ ei, int E, const int* __restrict__ flag,
                            int* __restrict__ cnt){
  int e = blockIdx.x * blockDim.x + threadIdx.x;
  if (e >= E) return;
  int dst = (*flag) ? ei[2*E + 2*e] : ei[E + e];
  atomicAdd(&cnt[dst], 1);
}

#define SCAN_T 1024
__global__ void scan_kernel(const int* __restrict__ cnt, int* __restrict__ row_ptr, int n){
  __shared__ int sm[SCAN_T];
  int t = threadIdx.x;
  int chunk = (n + SCAN_T - 1) / SCAN_T;
  int lo = t * chunk, hi = lo + chunk; if (hi > n) hi = n; if (lo > n) lo = n;
  int s = 0;
  for (int i = lo; i < hi; i++) s += cnt[i];
  sm[t] = s; __syncthreads();
  for (int off = 1; off < SCAN_T; off <<= 1){
    int v = (t >= off) ? sm[t - off] : 0;
    __syncthreads();
    sm[t] += v;
    __syncthreads();
  }
  int base = sm[t] - s; // exclusive prefix
  for (int i = lo; i < hi; i++){ row_ptr[i] = base; base += cnt[i]; }
  if (t == 0) row_ptr[n] = sm[SCAN_T - 1];
}

__global__ void selfloop_kernel(const int* __restrict__ row_ptr, int* __restrict__ col, int n){
  int i = blockIdx.x * blockDim.x + threadIdx.x;
  if (i < n) col[row_ptr[i]] = i;
}

__global__ void fill_edges(const int* __restrict__ ei, int E, const int* __restrict__ flag,
                           const int* __restrict__ row_ptr, int* __restrict__ fillpos,
                           int* __restrict__ col){
  int e = blockIdx.x * blockDim.x + threadIdx.x;
  if (e >= E) return;
  int f = *flag;
  int src = f ? ei[2*e]       : ei[e];
  int dst = f ? ei[2*E + 2*e] : ei[E + e];
  int off = atomicAdd(&fillpos[dst], 1);
  col[row_ptr[dst] + off] = src;
}

// ---------------- converts ----------------

__global__ void split_convert(const float* __restrict__ X, u16* __restrict__ Xh,
                              u16* __restrict__ Xl, long n){
  long i = blockIdx.x * (long)blockDim.x + threadIdx.x;
  if (i >= n) return;
  float v = X[i];
  u16 h = f2bf(v);
  Xh[i] = h;
  Xl[i] = f2bf(v - bf2f(h));
}

// W [K][N] fp32 -> WT [N][K] split bf16 (tiled transpose)
__global__ void convert_wT(const float* __restrict__ W, u16* __restrict__ Th,
                           u16* __restrict__ Tl, int K, int N){
  __shared__ float sm[32][33];
  int kb = blockIdx.x * 32, nb = blockIdx.y * 32;
  int tx = threadIdx.x, ty = threadIdx.y; // (32,8)
  for (int i = 0; i < 32; i += 8)
    sm[ty + i][tx] = W[(size_t)(kb + ty + i) * N + nb + tx];
  __syncthreads();
  for (int i = 0; i < 32; i += 8){
    float v = sm[tx][ty + i];
    u16 h = f2bf(v);
    size_t o = (size_t)(nb + ty + i) * K + kb + tx;
    Th[o] = h;
    Tl[o] = f2bf(v - bf2f(h));
  }
}

// ---------------- split-bf16 MFMA GEMM ----------------
// C[M][N] = A[M][K] @ B[K][N], A given row-major split bf16, B given as WT[N][K] split bf16.
// EPI 0: write fp32 C.  EPI 1: v = leakyrelu(v + bias[n]); write split bf16 Oh/Ol.

#define LDK 56

template<int EPI>
__global__ __launch_bounds__(256) void gemm_kernel(
    const u16* __restrict__ Ah, const u16* __restrict__ Al,
    const u16* __restrict__ Bh, const u16* __restrict__ Bl,
    float* __restrict__ C, u16* __restrict__ Oh, u16* __restrict__ Ol,
    const float* __restrict__ bias, int M, int N, int K)
{
  __shared__ u16 AsH[64 * LDK];
  __shared__ u16 AsL[64 * LDK];
  __shared__ u16 BsH[64 * LDK];
  __shared__ u16 BsL[64 * LDK];

  int tid = threadIdx.x;
  int bm = blockIdx.x, bn = blockIdx.y;
  int w = tid >> 6, lane = tid & 63;
  int wr = w >> 1, wc = w & 1;          // 2x2 waves of 32x32
  int lm = lane & 15, lk = (lane >> 4) * 8;

  f32x4 acc[2][2] = {};

  int srow = tid >> 2;                  // 0..63
  int skk  = (tid & 3) * 8;             // 0,8,16,24
  long arow = (long)bm * 64 + srow;
  bool aval = arow < M;
  long brow = (long)bn * 64 + srow;     // N multiple of 64 -> always valid

  const uint4 z4 = {0u, 0u, 0u, 0u};

  for (int k0 = 0; k0 < K; k0 += 32){
    uint4 avh = z4, avl = z4;
    if (aval){
      avh = *(const uint4*)(Ah + arow * (size_t)K + k0 + skk);
      avl = *(const uint4*)(Al + arow * (size_t)K + k0 + skk);
    }
    uint4 bvh = *(const uint4*)(Bh + brow * (size_t)K + k0 + skk);
    uint4 bvl = *(const uint4*)(Bl + brow * (size_t)K + k0 + skk);
    __syncthreads();
    *(uint4*)&AsH[srow * LDK + skk] = avh;
    *(uint4*)&AsL[srow * LDK + skk] = avl;
    *(uint4*)&BsH[srow * LDK + skk] = bvh;
    *(uint4*)&BsL[srow * LDK + skk] = bvl;
    __syncthreads();

    bf16x8 ah[2], alo[2], bh[2], blo[2];
    #pragma unroll
    for (int f = 0; f < 2; f++){
      int ar = (wr * 32 + f * 16 + lm) * LDK + lk;
      int br = (wc * 32 + f * 16 + lm) * LDK + lk;
      ah[f]  = ldfrag(&AsH[ar]);
      alo[f] = ldfrag(&AsL[ar]);
      bh[f]  = ldfrag(&BsH[br]);
      blo[f] = ldfrag(&BsL[br]);
    }
    #pragma unroll
    for (int fi = 0; fi < 2; fi++)
      #pragma unroll
      for (int fj = 0; fj < 2; fj++){
        acc[fi][fj] = __builtin_amdgcn_mfma_f32_16x16x32_bf16(ah[fi],  bh[fj],  acc[fi][fj], 0, 0, 0);
        acc[fi][fj] = __builtin_amdgcn_mfma_f32_16x16x32_bf16(ah[fi],  blo[fj], acc[fi][fj], 0, 0, 0);
        acc[fi][fj] = __builtin_amdgcn_mfma_f32_16x16x32_bf16(alo[fi], bh[fj],  acc[fi][fj], 0, 0, 0);
      }
  }

  #pragma unroll
  for (int fi = 0; fi < 2; fi++){
    int mbase = bm * 64 + wr * 32 + fi * 16 + ((lane >> 4) << 2);
    #pragma unroll
    for (int fj = 0; fj < 2; fj++){
      int n = bn * 64 + wc * 32 + fj * 16 + lm;
      #pragma unroll
      for (int j = 0; j < 4; j++){
        int m = mbase + j;
        if (m < M){
          float v = acc[fi][fj][j];
          size_t o = (size_t)m * N + n;
          if (EPI == 0){
            C[o] = v;
          } else {
            v += bias[n];
            v = v > 0.0f ? v : 0.2f * v;
            u16 h = f2bf(v);
            Oh[o] = h;
            Ol[o] = f2bf(v - bf2f(h));
          }
        }
      }
    }
  }
}

// ---------------- attention coefficients ----------------

template<int HEADS, int CH>
__global__ __launch_bounds__(256) void alpha_kernel(
    const float* __restrict__ H, const float* __restrict__ a_s, const float* __restrict__ a_d,
    float* __restrict__ asrc, float* __restrict__ adst, int Nn)
{
  int gw = blockIdx.x * 4 + (threadIdx.x >> 6);
  int lane = threadIdx.x & 63;
  int node = gw / HEADS, hd = gw % HEADS;
  if (node >= Nn) return;
  const float* hp  = H + (size_t)node * HEADS * CH + hd * CH;
  const float* asp = a_s + hd * CH;
  const float* adp = a_d + hd * CH;
  float s1 = 0.0f, s2 = 0.0f;
  #pragma unroll
  for (int i = 0; i < CH / 256; i++){
    int off = i * 256 + lane * 4;
    float4 h4 = *(const float4*)(hp + off);
    float4 s4 = *(const float4*)(asp + off);
    float4 d4 = *(const float4*)(adp + off);
    s1 += h4.x * s4.x + h4.y * s4.y + h4.z * s4.z + h4.w * s4.w;
    s2 += h4.x * d4.x + h4.y * d4.y + h4.z * d4.z + h4.w * d4.w;
  }
  for (int off = 32; off; off >>= 1){
    s1 += __shfl_xor(s1, off);
    s2 += __shfl_xor(s2, off);
  }
  if (lane == 0){ asrc[gw] = s1; adst[gw] = s2; }
}

template<int HEADS>
__global__ __launch_bounds__(256) void softmax_kernel(
    const int* __restrict__ row_ptr, const int* __restrict__ col,
    const float* __restrict__ asrc, const float* __restrict__ adst,
    float* __restrict__ alpha, int Nn)
{
  int dst = blockIdx.x * 4 + (threadIdx.x >> 6);
  int lane = threadIdx.x & 63;
  if (dst >= Nn) return;
  const int hd = (HEADS == 8) ? (lane & 7) : 0;
  const int el = (HEADS == 8) ? (lane >> 3) : lane;
  const int EPP = 64 / HEADS;
  int s = row_ptr[dst], e = row_ptr[dst + 1];
  float ad = adst[dst * HEADS + hd];
  float m = -1e30f;
  for (int p = s + el; p < e; p += EPP){
    float v = asrc[col[p] * HEADS + hd] + ad;
    v = v > 0.0f ? v : 0.2f * v;
    m = fmaxf(m, v);
  }
  for (int off = HEADS; off < 64; off <<= 1) m = fmaxf(m, __shfl_xor(m, off));
  float sum = 0.0f;
  for (int p = s + el; p < e; p += EPP){
    float v = asrc[col[p] * HEADS + hd] + ad;
    v = v > 0.0f ? v : 0.2f * v;
    sum += __expf(v - m);
  }
  for (int off = HEADS; off < 64; off <<= 1) sum += __shfl_xor(sum, off);
  float inv = 1.0f / (sum + 1e-16f);
  for (int p = s + el; p < e; p += EPP){
    float v = asrc[col[p] * HEADS + hd] + ad;
    v = v > 0.0f ? v : 0.2f * v;
    alpha[p * HEADS + hd] = __expf(v - m) * inv;
  }
}

// ---------------- aggregation ----------------

template<int F, int CH, bool FINAL>
__global__ __launch_bounds__(256) void agg_kernel(
    const float* __restrict__ H, const float* __restrict__ alpha,
    const int* __restrict__ row_ptr, const int* __restrict__ col,
    const float* __restrict__ bias,
    u16* __restrict__ Oh, u16* __restrict__ Ol, float* __restrict__ Ofp)
{
  constexpr int CPT = F / 256;
  constexpr int HEADS = F / CH;
  int dst = blockIdx.x;
  int t = threadIdx.x;
  int c0 = t * CPT;
  int hd = c0 / CH;
  float acc[CPT] = {};
  int s = row_ptr[dst], e = row_ptr[dst + 1];
  for (int p = s; p < e; p++){
    int src = col[p];
    float al = alpha[p * HEADS + hd];
    const float* hp = H + (size_t)src * F + c0;
    if (CPT == 8){
      float4 a = *(const float4*)hp;
      float4 b = *(const float4*)(hp + 4);
      acc[0] += al * a.x; acc[1] += al * a.y; acc[2] += al * a.z; acc[3] += al * a.w;
      acc[4] += al * b.x; acc[5] += al * b.y; acc[6] += al * b.z; acc[7] += al * b.w;
    } else {
      float2 a = *(const float2*)hp;
      acc[0] += al * a.x; acc[1] += al * a.y;
    }
  }
  #pragma unroll
  for (int i = 0; i < CPT; i++){
    float v = acc[i] + bias[c0 + i];
    v = v > 0.0f ? v : 0.2f * v;
    size_t o = (size_t)dst * F + c0 + i;
    if (FINAL){
      Ofp[o] = v;
    } else {
      u16 h = f2bf(v);
      Oh[o] = h;
      Ol[o] = f2bf(v - bf2f(h));
    }
  }
}

// ---------------- launcher ----------------

extern "C" void kernel_launch(void* const* d_in, const int* in_sizes, int n_in,
                              void* d_out, int out_size, void* d_ws, size_t ws_size,
                              hipStream_t stream)
{
  const float* x    = (const float*)d_in[0];
  const int*   ei   = (const int*)d_in[1];
  const float* W_in = (const float*)d_in[2];
  const float* b_in = (const float*)d_in[3];
  const float* W1   = (const float*)d_in[4];
  const float* as1  = (const float*)d_in[5];
  const float* ad1  = (const float*)d_in[6];
  const float* b1   = (const float*)d_in[7];
  const float* W2   = (const float*)d_in[8];
  const float* as2  = (const float*)d_in[9];
  const float* ad2  = (const float*)d_in[10];
  const float* b2   = (const float*)d_in[11];
  const float* W3   = (const float*)d_in[12];
  const float* as3  = (const float*)d_in[13];
  const float* ad3  = (const float*)d_in[14];
  const float* b3   = (const float*)d_in[15];

  const int N  = in_sizes[0] / 32;   // 10000
  const int E  = in_sizes[1] / 2;    // 80000
  const int ET = E + N;              // with self loops

  char* w = (char*)d_ws;
  size_t off = 0;
  auto carve = [&](size_t bytes) -> char* {
    off = (off + 255) & ~(size_t)255;
    char* p = w + off;
    off += bytes;
    return p;
  };

  int* flag    = (int*)carve(4);
  int* cnt     = (int*)carve((size_t)N * 4);
  int* fillpos = (int*)carve((size_t)N * 4);
  int* row_ptr = (int*)carve((size_t)(N + 1) * 4);
  int* col     = (int*)carve((size_t)ET * 4);
  u16* xh      = (u16*)carve((size_t)N * 32 * 2);
  u16* xl      = (u16*)carve((size_t)N * 32 * 2);
  u16* h0h     = (u16*)carve((size_t)N * 128 * 2);
  u16* h0l     = (u16*)carve((size_t)N * 128 * 2);
  u16* WTh     = (u16*)carve((size_t)2048 * 2048 * 2);
  u16* WTl     = (u16*)carve((size_t)2048 * 2048 * 2);
  float* Hbuf  = (float*)carve((size_t)N * 2048 * 4);
  u16* XBh     = (u16*)carve((size_t)N * 2048 * 2);
  u16* XBl     = (u16*)carve((size_t)N * 2048 * 2);
  float* asrc  = (float*)carve((size_t)N * 8 * 4);
  float* adst  = (float*)carve((size_t)N * 8 * 4);
  float* alpha = (float*)carve((size_t)ET * 8 * 4);

  if (off > ws_size) return; // workspace too small: fail visibly (output stays zero)

  const int MT = (N + 63) / 64;   // 157 row-tiles
  float* out = (float*)d_out;

  // CSR build
  detect_kernel<<<1, 1, 0, stream>>>(ei, flag);
  init_kernel<<<(N + 255) / 256, 256, 0, stream>>>(cnt, fillpos, N);
  count_edges<<<(E + 255) / 256, 256, 0, stream>>>(ei, E, flag, cnt);
  scan_kernel<<<1, SCAN_T, 0, stream>>>(cnt, row_ptr, N);
  selfloop_kernel<<<(N + 255) / 256, 256, 0, stream>>>(row_ptr, col, N);
  fill_edges<<<(E + 255) / 256, 256, 0, stream>>>(ei, E, flag, row_ptr, fillpos, col);

  // input projection: h0 = lrelu(x @ W_in + b_in), emitted as split bf16
  split_convert<<<((long)N * 32 + 255) / 256, 256, 0, stream>>>(x, xh, xl, (long)N * 32);
  convert_wT<<<dim3(1, 4), dim3(32, 8), 0, stream>>>(W_in, WTh, WTl, 32, 128);
  gemm_kernel<1><<<dim3(MT, 2), 256, 0, stream>>>(xh, xl, WTh, WTl,
      nullptr, h0h, h0l, b_in, N, 128, 32);

  // ---- GAT layer 1: 128 -> 8x256 ----
  convert_wT<<<dim3(4, 64), dim3(32, 8), 0, stream>>>(W1, WTh, WTl, 128, 2048);
  gemm_kernel<0><<<dim3(MT, 32), 256, 0, stream>>>(h0h, h0l, WTh, WTl,
      Hbuf, nullptr, nullptr, nullptr, N, 2048, 128);
  alpha_kernel<8, 256><<<(N * 8 + 3) / 4, 256, 0, stream>>>(Hbuf, as1, ad1, asrc, adst, N);
  softmax_kernel<8><<<(N + 3) / 4, 256, 0, stream>>>(row_ptr, col, asrc, adst, alpha, N);
  agg_kernel<2048, 256, false><<<N, 256, 0, stream>>>(Hbuf, alpha, row_ptr, col, b1,
      XBh, XBl, nullptr);

  // ---- GAT layer 2: 2048 -> 8x256 ----
  convert_wT<<<dim3(64, 64), dim3(32, 8), 0, stream>>>(W2, WTh, WTl, 2048, 2048);
  gemm_kernel<0><<<dim3(MT, 32), 256, 0, stream>>>(XBh, XBl, WTh, WTl,
      Hbuf, nullptr, nullptr, nullptr, N, 2048, 2048);
  alpha_kernel<8, 256><<<(N * 8 + 3) / 4, 256, 0, stream>>>(Hbuf, as2, ad2, asrc, adst, N);
  softmax_kernel<8><<<(N + 3) / 4, 256, 0, stream>>>(row_ptr, col, asrc, adst, alpha, N);
  agg_kernel<2048, 256, false><<<N, 256, 0, stream>>>(Hbuf, alpha, row_ptr, col, b2,
      XBh, XBl, nullptr);

  // ---- GAT layer 3: 2048 -> 1x512 ----
  convert_wT<<<dim3(64, 16), dim3(32, 8), 0, stream>>>(W3, WTh, WTl, 2048, 512);
  gemm_kernel<0><<<dim3(MT, 8), 256, 0, stream>>>(XBh, XBl, WTh, WTl,
      Hbuf, nullptr, nullptr, nullptr, N, 512, 2048);
  alpha_kernel<1, 512><<<(N + 3) / 4, 256, 0, stream>>>(Hbuf, as3, ad3, asrc, adst, N);
  softmax_kernel<1><<<(N + 3) / 4, 256, 0, stream>>>(row_ptr, col, asrc, adst, alpha, N);
  agg_kernel<512, 512, true><<<N, 256, 0, stream>>>(Hbuf, alpha, row_ptr, col, b3,
      nullptr, nullptr, out);
}

// Round 2
// 657.392 us; speedup vs baseline: 1.5363x; 1.5363x over previous
//
#include <hip/hip_runtime.h>

typedef unsigned short u16;
typedef unsigned int u32;
typedef __bf16 bf16_t;
typedef bf16_t bf16x8 __attribute__((ext_vector_type(8)));
typedef float f32x4 __attribute__((ext_vector_type(4)));

__device__ __forceinline__ u16 f2bf(float f){
  u32 u = __float_as_uint(f);
  u32 r = (u + 0x7fffu + ((u >> 16) & 1u)) >> 16;
  return (u16)r;
}
__device__ __forceinline__ float bf2f(u16 h){
  return __uint_as_float(((u32)h) << 16);
}
__device__ __forceinline__ bf16x8 ldfrag(const u16* p){
  union { uint4 u; bf16x8 b; } x;
  x.u = *(const uint4*)p;
  return x.b;
}
__device__ __forceinline__ void gload_lds16(const u16* g, u16* l){
  __builtin_amdgcn_global_load_lds(
      (const __attribute__((address_space(1))) u32*)g,
      (__attribute__((address_space(3))) u32*)l, 16, 0, 0);
}

// ---------------- CSR build ----------------

__global__ void detect_kernel(const int* __restrict__ ei, int* __restrict__ flag){
  if (threadIdx.x == 0 && blockIdx.x == 0){
    int orv = 0;
    for (int i = 0; i < 200; i++) orv |= ei[2*i + 1];
    *flag = (orv == 0) ? 1 : 0;
  }
}

__global__ void init_kernel(int* __restrict__ cnt, int* __restrict__ fillpos, int n){
  int i = blockIdx.x * blockDim.x + threadIdx.x;
  if (i < n){ cnt[i] = 1; fillpos[i] = 1; } // slot 0 = self loop
}

__global__ void count_edges(const int* __restrict__ ei, int E, const int* __restrict__ flag,
                            int* __restrict__ cnt){
  int e = blockIdx.x * blockDim.x + threadIdx.x;
  if (e >= E) return;
  int dst = (*flag) ? ei[2*E + 2*e] : ei[E + e];
  atomicAdd(&cnt[dst], 1);
}

#define SCAN_T 1024
__global__ void scan_kernel(const int* __restrict__ cnt, int* __restrict__ row_ptr, int n){
  __shared__ int sm[SCAN_T];
  int t = threadIdx.x;
  int chunk = (n + SCAN_T - 1) / SCAN_T;
  int lo = t * chunk, hi = lo + chunk; if (hi > n) hi = n; if (lo > n) lo = n;
  int s = 0;
  for (int i = lo; i < hi; i++) s += cnt[i];
  sm[t] = s; __syncthreads();
  for (int off = 1; off < SCAN_T; off <<= 1){
    int v = (t >= off) ? sm[t - off] : 0;
    __syncthreads();
    sm[t] += v;
    __syncthreads();
  }
  int base = sm[t] - s;
  for (int i = lo; i < hi; i++){ row_ptr[i] = base; base += cnt[i]; }
  if (t == 0) row_ptr[n] = sm[SCAN_T - 1];
}

__global__ void selfloop_kernel(const int* __restrict__ row_ptr, int* __restrict__ col, int n){
  int i = blockIdx.x * blockDim.x + threadIdx.x;
  if (i < n) col[row_ptr[i]] = i;
}

__global__ void fill_edges(const int* __restrict__ ei, int E, const int* __restrict__ flag,
                           const int* __restrict__ row_ptr, int* __restrict__ fillpos,
                           int* __restrict__ col){
  int e = blockIdx.x * blockDim.x + threadIdx.x;
  if (e >= E) return;
  int f = *flag;
  int src = f ? ei[2*e]       : ei[e];
  int dst = f ? ei[2*E + 2*e] : ei[E + e];
  int off = atomicAdd(&fillpos[dst], 1);
  col[row_ptr[dst] + off] = src;
}

// ---------------- converts ----------------

__global__ void split_convert(const float* __restrict__ X, u16* __restrict__ Xh,
                              u16* __restrict__ Xl, long n){
  long i = blockIdx.x * (long)blockDim.x + threadIdx.x;
  if (i >= n) return;
  float v = X[i];
  u16 h = f2bf(v);
  Xh[i] = h;
  Xl[i] = f2bf(v - bf2f(h));
}

// W [K][N] fp32 -> WT [N][K] split bf16 (tiled transpose)
__global__ void convert_wT(const float* __restrict__ W, u16* __restrict__ Th,
                           u16* __restrict__ Tl, int K, int N){
  __shared__ float sm[32][33];
  int kb = blockIdx.x * 32, nb = blockIdx.y * 32;
  int tx = threadIdx.x, ty = threadIdx.y; // (32,8)
  for (int i = 0; i < 32; i += 8)
    sm[ty + i][tx] = W[(size_t)(kb + ty + i) * N + nb + tx];
  __syncthreads();
  for (int i = 0; i < 32; i += 8){
    float v = sm[tx][ty + i];
    u16 h = f2bf(v);
    size_t o = (size_t)(nb + ty + i) * K + kb + tx;
    Th[o] = h;
    Tl[o] = f2bf(v - bf2f(h));
  }
}

// ---------------- split-bf16 MFMA GEMM (m97 structure) ----------------
// C[M][N] = A[M][K] @ B[K][N]; A row-major split bf16, B as WT[N][K] split bf16.
// 128x128 tile, 4 waves (2x2) each 64x64 = 4x4 16x16x32 frags, BK=32,
// global_load_lds staging into linear LDS [128][32].
// EPI 0: fp32 C.  EPI 1: bias+lrelu, split bf16 (Oh,Ol).  EPI 2: bf16 Cb.

template<int EPI>
__global__ __launch_bounds__(256) void gemm_kernel(
    const u16* __restrict__ Ah, const u16* __restrict__ Al,
    const u16* __restrict__ Bh, const u16* __restrict__ Bl,
    float* __restrict__ C, u16* __restrict__ Cb,
    u16* __restrict__ Oh, u16* __restrict__ Ol,
    const float* __restrict__ bias, int M, int N, int K, int nbm, int nbn)
{
  __shared__ u16 sAh[128*32];
  __shared__ u16 sAl[128*32];
  __shared__ u16 sBh[128*32];
  __shared__ u16 sBl[128*32];

  // bijective XCD swizzle (m204)
  int nwg = nbm * nbn;
  int bid = blockIdx.x;
  int q = nwg >> 3, r = nwg & 7;
  int xcd = bid & 7, idx = bid >> 3;
  int wg = (xcd < r ? xcd * (q + 1) : r * (q + 1) + (xcd - r) * q) + idx;
  int bm = wg / nbn, bn = wg % nbn;

  int tid = threadIdx.x;
  int lane = tid & 63;
  int w = tid >> 6;
  int wr = (w >> 1) * 64, wc = (w & 1) * 64;
  int lm = lane & 15, lk = (lane >> 4) * 8;

  // staging coords: thread t covers row t/4 (+64 for issue 1), k-chunk (t%4)*8
  int sk = (tid & 3) * 8;
  long ar0 = (long)bm * 128 + (tid >> 2);
  long ar1 = ar0 + 64;
  if (ar0 >= M) ar0 = M - 1;   // clamped rows only feed unstored outputs
  if (ar1 >= M) ar1 = M - 1;
  long br0 = (long)bn * 128 + (tid >> 2);  // N multiple of 128
  long br1 = br0 + 64;

  const u16* pAh0 = Ah + ar0 * K + sk;  const u16* pAh1 = Ah + ar1 * K + sk;
  const u16* pAl0 = Al + ar0 * K + sk;  const u16* pAl1 = Al + ar1 * K + sk;
  const u16* pBh0 = Bh + br0 * K + sk;  const u16* pBh1 = Bh + br1 * K + sk;
  const u16* pBl0 = Bl + br0 * K + sk;  const u16* pBl1 = Bl + br1 * K + sk;
  u16* dst0 = sAh + tid * 8;  // generic template of dest offsets (per array)
  int d1 = 2048;              // issue-1 element offset (64 rows * 32)

  f32x4 acc[4][4] = {};

  for (int k0 = 0; k0 < K; k0 += 32){
    gload_lds16(pAh0 + k0, sAh + tid * 8);
    gload_lds16(pAh1 + k0, sAh + d1 + tid * 8);
    gload_lds16(pAl0 + k0, sAl + tid * 8);
    gload_lds16(pAl1 + k0, sAl + d1 + tid * 8);
    gload_lds16(pBh0 + k0, sBh + tid * 8);
    gload_lds16(pBh1 + k0, sBh + d1 + tid * 8);
    gload_lds16(pBl0 + k0, sBl + tid * 8);
    gload_lds16(pBl1 + k0, sBl + d1 + tid * 8);
    __syncthreads();   // compiler drains vmcnt(0) before barrier

    bf16x8 ah[4], al[4], bh[4], bl[4];
    #pragma unroll
    for (int f = 0; f < 4; f++){
      int arow = wr + f * 16 + lm;
      int brow = wc + f * 16 + lm;
      ah[f] = ldfrag(sAh + arow * 32 + lk);
      al[f] = ldfrag(sAl + arow * 32 + lk);
      bh[f] = ldfrag(sBh + brow * 32 + lk);
      bl[f] = ldfrag(sBl + brow * 32 + lk);
    }
    #pragma unroll
    for (int fi = 0; fi < 4; fi++)
      #pragma unroll
      for (int fj = 0; fj < 4; fj++){
        acc[fi][fj] = __builtin_amdgcn_mfma_f32_16x16x32_bf16(ah[fi], bh[fj], acc[fi][fj], 0, 0, 0);
        acc[fi][fj] = __builtin_amdgcn_mfma_f32_16x16x32_bf16(ah[fi], bl[fj], acc[fi][fj], 0, 0, 0);
        acc[fi][fj] = __builtin_amdgcn_mfma_f32_16x16x32_bf16(al[fi], bh[fj], acc[fi][fj], 0, 0, 0);
      }
    __syncthreads();   // all waves done reading before next overwrite
  }
  (void)dst0;

  #pragma unroll
  for (int fi = 0; fi < 4; fi++){
    int mb = bm * 128 + wr + fi * 16 + ((lane >> 4) << 2);
    #pragma unroll
    for (int fj = 0; fj < 4; fj++){
      int n = bn * 128 + wc + fj * 16 + lm;
      #pragma unroll
      for (int j = 0; j < 4; j++){
        int m = mb + j;
        if (m < M){
          float v = acc[fi][fj][j];
          size_t o = (size_t)m * N + n;
          if (EPI == 0){
            C[o] = v;
          } else if (EPI == 2){
            Cb[o] = f2bf(v);
          } else {
            v += bias[n];
            v = v > 0.0f ? v : 0.2f * v;
            u16 h = f2bf(v);
            Oh[o] = h;
            Ol[o] = f2bf(v - bf2f(h));
          }
        }
      }
    }
  }
}

// ---------------- attention coefficients ----------------

template<int HEADS, int CH, bool BF>
__global__ __launch_bounds__(256) void alpha_kernel(
    const void* __restrict__ Hv, const float* __restrict__ a_s, const float* __restrict__ a_d,
    float* __restrict__ asrc, float* __restrict__ adst, int Nn)
{
  int gw = blockIdx.x * 4 + (threadIdx.x >> 6);
  int lane = threadIdx.x & 63;
  int node = gw / HEADS, hd = gw % HEADS;
  if (node >= Nn) return;
  size_t base = (size_t)node * HEADS * CH + hd * CH;
  const float* asp = a_s + hd * CH;
  const float* adp = a_d + hd * CH;
  float s1 = 0.0f, s2 = 0.0f;
  #pragma unroll
  for (int i = 0; i < CH / 256; i++){
    int off = i * 256 + lane * 4;
    float h0, h1, h2, h3;
    if (BF){
      ushort4 u = *(const ushort4*)((const u16*)Hv + base + off);
      h0 = bf2f(u.x); h1 = bf2f(u.y); h2 = bf2f(u.z); h3 = bf2f(u.w);
    } else {
      float4 f = *(const float4*)((const float*)Hv + base + off);
      h0 = f.x; h1 = f.y; h2 = f.z; h3 = f.w;
    }
    float4 s4 = *(const float4*)(asp + off);
    float4 d4 = *(const float4*)(adp + off);
    s1 += h0 * s4.x + h1 * s4.y + h2 * s4.z + h3 * s4.w;
    s2 += h0 * d4.x + h1 * d4.y + h2 * d4.z + h3 * d4.w;
  }
  for (int off = 32; off; off >>= 1){
    s1 += __shfl_xor(s1, off);
    s2 += __shfl_xor(s2, off);
  }
  if (lane == 0){ asrc[gw] = s1; adst[gw] = s2; }
}

template<int HEADS>
__global__ __launch_bounds__(256) void softmax_kernel(
    const int* __restrict__ row_ptr, const int* __restrict__ col,
    const float* __restrict__ asrc, const float* __restrict__ adst,
    float* __restrict__ alpha, int Nn)
{
  int dst = blockIdx.x * 4 + (threadIdx.x >> 6);
  int lane = threadIdx.x & 63;
  if (dst >= Nn) return;
  const int hd = (HEADS == 8) ? (lane & 7) : 0;
  const int el = (HEADS == 8) ? (lane >> 3) : lane;
  const int EPP = 64 / HEADS;
  int s = row_ptr[dst], e = row_ptr[dst + 1];
  float ad = adst[dst * HEADS + hd];
  float m = -1e30f;
  for (int p = s + el; p < e; p += EPP){
    float v = asrc[col[p] * HEADS + hd] + ad;
    v = v > 0.0f ? v : 0.2f * v;
    m = fmaxf(m, v);
  }
  for (int off = HEADS; off < 64; off <<= 1) m = fmaxf(m, __shfl_xor(m, off));
  float sum = 0.0f;
  for (int p = s + el; p < e; p += EPP){
    float v = asrc[col[p] * HEADS + hd] + ad;
    v = v > 0.0f ? v : 0.2f * v;
    sum += __expf(v - m);
  }
  for (int off = HEADS; off < 64; off <<= 1) sum += __shfl_xor(sum, off);
  float inv = 1.0f / (sum + 1e-16f);
  for (int p = s + el; p < e; p += EPP){
    float v = asrc[col[p] * HEADS + hd] + ad;
    v = v > 0.0f ? v : 0.2f * v;
    alpha[p * HEADS + hd] = __expf(v - m) * inv;
  }
}

// ---------------- aggregation ----------------

template<int F, int CH, bool FINAL, bool BF>
__global__ __launch_bounds__(256) void agg_kernel(
    const void* __restrict__ Hv, const float* __restrict__ alpha,
    const int* __restrict__ row_ptr, const int* __restrict__ col,
    const float* __restrict__ bias,
    u16* __restrict__ Oh, u16* __restrict__ Ol, float* __restrict__ Ofp)
{
  constexpr int CPT = F / 256;
  constexpr int HEADS = F / CH;
  int dst = blockIdx.x;
  int t = threadIdx.x;
  int c0 = t * CPT;
  int hd = c0 / CH;
  float acc[CPT] = {};
  int s = row_ptr[dst], e = row_ptr[dst + 1];
  for (int p = s; p < e; p++){
    int src = col[p];
    float al = alpha[p * HEADS + hd];
    if (BF){
      const u16* hp = (const u16*)Hv + (size_t)src * F + c0;
      if (CPT == 8){
        ushort4 a = *(const ushort4*)hp;
        ushort4 b = *(const ushort4*)(hp + 4);
        acc[0] += al * bf2f(a.x); acc[1] += al * bf2f(a.y);
        acc[2] += al * bf2f(a.z); acc[3] += al * bf2f(a.w);
        acc[4] += al * bf2f(b.x); acc[5] += al * bf2f(b.y);
        acc[6] += al * bf2f(b.z); acc[7] += al * bf2f(b.w);
      } else {
        ushort2 a = *(const ushort2*)hp;
        acc[0] += al * bf2f(a.x); acc[1] += al * bf2f(a.y);
      }
    } else {
      const float* hp = (const float*)Hv + (size_t)src * F + c0;
      if (CPT == 8){
        float4 a = *(const float4*)hp;
        float4 b = *(const float4*)(hp + 4);
        acc[0] += al * a.x; acc[1] += al * a.y; acc[2] += al * a.z; acc[3] += al * a.w;
        acc[4] += al * b.x; acc[5] += al * b.y; acc[6] += al * b.z; acc[7] += al * b.w;
      } else {
        float2 a = *(const float2*)hp;
        acc[0] += al * a.x; acc[1] += al * a.y;
      }
    }
  }
  #pragma unroll
  for (int i = 0; i < CPT; i++){
    float v = acc[i] + bias[c0 + i];
    v = v > 0.0f ? v : 0.2f * v;
    size_t o = (size_t)dst * F + c0 + i;
    if (FINAL){
      Ofp[o] = v;
    } else {
      u16 h = f2bf(v);
      Oh[o] = h;
      Ol[o] = f2bf(v - bf2f(h));
    }
  }
}

// ---------------- launcher ----------------

extern "C" void kernel_launch(void* const* d_in, const int* in_sizes, int n_in,
                              void* d_out, int out_size, void* d_ws, size_t ws_size,
                              hipStream_t stream)
{
  const float* x    = (const float*)d_in[0];
  const int*   ei   = (const int*)d_in[1];
  const float* W_in = (const float*)d_in[2];
  const float* b_in = (const float*)d_in[3];
  const float* W1   = (const float*)d_in[4];
  const float* as1  = (const float*)d_in[5];
  const float* ad1  = (const float*)d_in[6];
  const float* b1   = (const float*)d_in[7];
  const float* W2   = (const float*)d_in[8];
  const float* as2  = (const float*)d_in[9];
  const float* ad2  = (const float*)d_in[10];
  const float* b2   = (const float*)d_in[11];
  const float* W3   = (const float*)d_in[12];
  const float* as3  = (const float*)d_in[13];
  const float* ad3  = (const float*)d_in[14];
  const float* b3   = (const float*)d_in[15];

  const int N  = in_sizes[0] / 32;   // 10000
  const int E  = in_sizes[1] / 2;    // 80000
  const int ET = E + N;

  char* w = (char*)d_ws;
  size_t off = 0;
  auto carve = [&](size_t bytes) -> char* {
    off = (off + 255) & ~(size_t)255;
    char* p = w + off;
    off += bytes;
    return p;
  };

  int* flag    = (int*)carve(4);
  int* cnt     = (int*)carve((size_t)N * 4);
  int* fillpos = (int*)carve((size_t)N * 4);
  int* row_ptr = (int*)carve((size_t)(N + 1) * 4);
  int* col     = (int*)carve((size_t)ET * 4);
  u16* xh      = (u16*)carve((size_t)N * 32 * 2);
  u16* xl      = (u16*)carve((size_t)N * 32 * 2);
  u16* h0h     = (u16*)carve((size_t)N * 128 * 2);
  u16* h0l     = (u16*)carve((size_t)N * 128 * 2);
  u16* WTh     = (u16*)carve((size_t)2048 * 2048 * 2);
  u16* WTl     = (u16*)carve((size_t)2048 * 2048 * 2);
  u16* Hb      = (u16*)carve((size_t)N * 2048 * 2);   // bf16 h for layers 1,2
  float* H3    = (float*)carve((size_t)N * 512 * 4);  // fp32 h for layer 3
  u16* XBh     = (u16*)carve((size_t)N * 2048 * 2);
  u16* XBl     = (u16*)carve((size_t)N * 2048 * 2);
  float* asrc  = (float*)carve((size_t)N * 8 * 4);
  float* adst  = (float*)carve((size_t)N * 8 * 4);
  float* alpha = (float*)carve((size_t)ET * 8 * 4);

  if (off > ws_size) return;

  const int MT = (N + 127) / 128;   // 79 row-tiles
  float* out = (float*)d_out;

  // CSR build
  detect_kernel<<<1, 1, 0, stream>>>(ei, flag);
  init_kernel<<<(N + 255) / 256, 256, 0, stream>>>(cnt, fillpos, N);
  count_edges<<<(E + 255) / 256, 256, 0, stream>>>(ei, E, flag, cnt);
  scan_kernel<<<1, SCAN_T, 0, stream>>>(cnt, row_ptr, N);
  selfloop_kernel<<<(N + 255) / 256, 256, 0, stream>>>(row_ptr, col, N);
  fill_edges<<<(E + 255) / 256, 256, 0, stream>>>(ei, E, flag, row_ptr, fillpos, col);

  // input projection: h0 = lrelu(x @ W_in + b_in) -> split bf16
  split_convert<<<((long)N * 32 + 255) / 256, 256, 0, stream>>>(x, xh, xl, (long)N * 32);
  convert_wT<<<dim3(1, 4), dim3(32, 8), 0, stream>>>(W_in, WTh, WTl, 32, 128);
  gemm_kernel<1><<<MT * 1, 256, 0, stream>>>(xh, xl, WTh, WTl,
      nullptr, nullptr, h0h, h0l, b_in, N, 128, 32, MT, 1);

  // ---- GAT layer 1: 128 -> 8x256 ----
  convert_wT<<<dim3(4, 64), dim3(32, 8), 0, stream>>>(W1, WTh, WTl, 128, 2048);
  gemm_kernel<2><<<MT * 16, 256, 0, stream>>>(h0h, h0l, WTh, WTl,
      nullptr, Hb, nullptr, nullptr, nullptr, N, 2048, 128, MT, 16);
  alpha_kernel<8, 256, true><<<(N * 8 + 3) / 4, 256, 0, stream>>>(Hb, as1, ad1, asrc, adst, N);
  softmax_kernel<8><<<(N + 3) / 4, 256, 0, stream>>>(row_ptr, col, asrc, adst, alpha, N);
  agg_kernel<2048, 256, false, true><<<N, 256, 0, stream>>>(Hb, alpha, row_ptr, col, b1,
      XBh, XBl, nullptr);

  // ---- GAT layer 2: 2048 -> 8x256 ----
  convert_wT<<<dim3(64, 64), dim3(32, 8), 0, stream>>>(W2, WTh, WTl, 2048, 2048);
  gemm_kernel<2><<<MT * 16, 256, 0, stream>>>(XBh, XBl, WTh, WTl,
      nullptr, Hb, nullptr, nullptr, nullptr, N, 2048, 2048, MT, 16);
  alpha_kernel<8, 256, true><<<(N * 8 + 3) / 4, 256, 0, stream>>>(Hb, as2, ad2, asrc, adst, N);
  softmax_kernel<8><<<(N + 3) / 4, 256, 0, stream>>>(row_ptr, col, asrc, adst, alpha, N);
  agg_kernel<2048, 256, false, true><<<N, 256, 0, stream>>>(Hb, alpha, row_ptr, col, b2,
      XBh, XBl, nullptr);

  // ---- GAT layer 3: 2048 -> 1x512 (fp32 h to protect final accuracy) ----
  convert_wT<<<dim3(64, 16), dim3(32, 8), 0, stream>>>(W3, WTh, WTl, 2048, 512);
  gemm_kernel<0><<<MT * 4, 256, 0, stream>>>(XBh, XBl, WTh, WTl,
      H3, nullptr, nullptr, nullptr, nullptr, N, 512, 2048, MT, 4);
  alpha_kernel<1, 512, false><<<(N + 3) / 4, 256, 0, stream>>>(H3, as3, ad3, asrc, adst, N);
  softmax_kernel<1><<<(N + 3) / 4, 256, 0, stream>>>(row_ptr, col, asrc, adst, alpha, N);
  agg_kernel<512, 512, true, false><<<N, 256, 0, stream>>>(H3, alpha, row_ptr, col, b3,
      nullptr, nullptr, out);
}

// Round 3
// 439.149 us; speedup vs baseline: 2.2998x; 1.4970x over previous
//
#include <hip/hip_runtime.h>

typedef unsigned short u16;
typedef unsigned int u32;
typedef _Float16 f16;
typedef f16 f16x8 __attribute__((ext_vector_type(8)));
typedef float f32x4 __attribute__((ext_vector_type(4)));

__device__ __forceinline__ float h2f(f16 h){ return (float)h; }
__device__ __forceinline__ f16 f2h(float f){ return (f16)f; }

__device__ __forceinline__ f16x8 ldfrag(const f16* p){
  union { uint4 u; f16x8 h; } x;
  x.u = *(const uint4*)p;
  return x.h;
}
__device__ __forceinline__ void gload_lds16(const f16* g, f16* l){
  __builtin_amdgcn_global_load_lds(
      (const __attribute__((address_space(1))) u32*)g,
      (__attribute__((address_space(3))) u32*)l, 16, 0, 0);
}

// ---------------- CSR build ----------------

__global__ void detect_kernel(const int* __restrict__ ei, int* __restrict__ flag){
  if (threadIdx.x == 0 && blockIdx.x == 0){
    int orv = 0;
    for (int i = 0; i < 200; i++) orv |= ei[2*i + 1];
    *flag = (orv == 0) ? 1 : 0;
  }
}

__global__ void init_kernel(int* __restrict__ cnt, int* __restrict__ fillpos, int n){
  int i = blockIdx.x * blockDim.x + threadIdx.x;
  if (i < n){ cnt[i] = 1; fillpos[i] = 1; } // slot 0 = self loop
}

__global__ void count_edges(const int* __restrict__ ei, int E, const int* __restrict__ flag,
                            int* __restrict__ cnt){
  int e = blockIdx.x * blockDim.x + threadIdx.x;
  if (e >= E) return;
  int dst = (*flag) ? ei[2*E + 2*e] : ei[E + e];
  atomicAdd(&cnt[dst], 1);
}

#define SCAN_T 1024
__global__ void scan_kernel(const int* __restrict__ cnt, int* __restrict__ row_ptr, int n){
  __shared__ int sm[SCAN_T];
  int t = threadIdx.x;
  int chunk = (n + SCAN_T - 1) / SCAN_T;
  int lo = t * chunk, hi = lo + chunk; if (hi > n) hi = n; if (lo > n) lo = n;
  int s = 0;
  for (int i = lo; i < hi; i++) s += cnt[i];
  sm[t] = s; __syncthreads();
  for (int off = 1; off < SCAN_T; off <<= 1){
    int v = (t >= off) ? sm[t - off] : 0;
    __syncthreads();
    sm[t] += v;
    __syncthreads();
  }
  int base = sm[t] - s;
  for (int i = lo; i < hi; i++){ row_ptr[i] = base; base += cnt[i]; }
  if (t == 0) row_ptr[n] = sm[SCAN_T - 1];
}

__global__ void selfloop_kernel(const int* __restrict__ row_ptr, int* __restrict__ col, int n){
  int i = blockIdx.x * blockDim.x + threadIdx.x;
  if (i < n) col[row_ptr[i]] = i;
}

__global__ void fill_edges(const int* __restrict__ ei, int E, const int* __restrict__ flag,
                           const int* __restrict__ row_ptr, int* __restrict__ fillpos,
                           int* __restrict__ col){
  int e = blockIdx.x * blockDim.x + threadIdx.x;
  if (e >= E) return;
  int f = *flag;
  int src = f ? ei[2*e]       : ei[e];
  int dst = f ? ei[2*E + 2*e] : ei[E + e];
  int off = atomicAdd(&fillpos[dst], 1);
  col[row_ptr[dst] + off] = src;
}

// ---------------- converts ----------------

__global__ void convert_f16(const float* __restrict__ X, f16* __restrict__ Xo, long n){
  long i = blockIdx.x * (long)blockDim.x + threadIdx.x;
  if (i >= n) return;
  Xo[i] = f2h(X[i]);
}

// W [K][N] fp32 -> WT [N][K] fp16 (tiled transpose)
__global__ void convert_wT(const float* __restrict__ W, f16* __restrict__ T, int K, int N){
  __shared__ float sm[32][33];
  int kb = blockIdx.x * 32, nb = blockIdx.y * 32;
  int tx = threadIdx.x, ty = threadIdx.y; // (32,8)
  for (int i = 0; i < 32; i += 8)
    sm[ty + i][tx] = W[(size_t)(kb + ty + i) * N + nb + tx];
  __syncthreads();
  for (int i = 0; i < 32; i += 8)
    T[(size_t)(nb + ty + i) * K + kb + tx] = f2h(sm[tx][ty + i]);
}

// ---------------- fp16 MFMA GEMM (m97 structure) ----------------
// C[M][N] = A[M][K] @ B[K][N]; A row-major fp16, B as WT[N][K] fp16.
// 128x128 tile, 4 waves (2x2) each 64x64 = 4x4 16x16x32 frags, BK=32,
// global_load_lds staging into linear LDS [128][32].
// EPI 0: fp32 C.  EPI 1: bias+lrelu -> fp16.  EPI 2: plain fp16.

template<int EPI>
__global__ __launch_bounds__(256) void gemm_kernel(
    const f16* __restrict__ A, const f16* __restrict__ B,
    float* __restrict__ C, f16* __restrict__ Ch,
    const float* __restrict__ bias, int M, int N, int K, int nbm, int nbn)
{
  __shared__ f16 sA[128*32];
  __shared__ f16 sB[128*32];

  // bijective XCD swizzle (m204)
  int nwg = nbm * nbn;
  int bid = blockIdx.x;
  int q = nwg >> 3, r = nwg & 7;
  int xcd = bid & 7, idx = bid >> 3;
  int wg = (xcd < r ? xcd * (q + 1) : r * (q + 1) + (xcd - r) * q) + idx;
  int bm = wg / nbn, bn = wg % nbn;

  int tid = threadIdx.x;
  int lane = tid & 63;
  int w = tid >> 6;
  int wr = (w >> 1) * 64, wc = (w & 1) * 64;
  int lm = lane & 15, lk = (lane >> 4) * 8;

  int sk = (tid & 3) * 8;
  long ar0 = (long)bm * 128 + (tid >> 2);
  long ar1 = ar0 + 64;
  if (ar0 >= M) ar0 = M - 1;   // clamped rows only feed unstored outputs
  if (ar1 >= M) ar1 = M - 1;
  long br0 = (long)bn * 128 + (tid >> 2);  // N multiple of 128
  long br1 = br0 + 64;

  const f16* pA0 = A + ar0 * K + sk;  const f16* pA1 = A + ar1 * K + sk;
  const f16* pB0 = B + br0 * K + sk;  const f16* pB1 = B + br1 * K + sk;
  const int d1 = 2048;  // 64 rows * 32 elems

  f32x4 acc[4][4] = {};

  for (int k0 = 0; k0 < K; k0 += 32){
    gload_lds16(pA0 + k0, sA + tid * 8);
    gload_lds16(pA1 + k0, sA + d1 + tid * 8);
    gload_lds16(pB0 + k0, sB + tid * 8);
    gload_lds16(pB1 + k0, sB + d1 + tid * 8);
    __syncthreads();   // drains vmcnt before barrier

    f16x8 af[4], bf[4];
    #pragma unroll
    for (int f = 0; f < 4; f++){
      af[f] = ldfrag(sA + (wr + f * 16 + lm) * 32 + lk);
      bf[f] = ldfrag(sB + (wc + f * 16 + lm) * 32 + lk);
    }
    #pragma unroll
    for (int fi = 0; fi < 4; fi++)
      #pragma unroll
      for (int fj = 0; fj < 4; fj++)
        acc[fi][fj] = __builtin_amdgcn_mfma_f32_16x16x32_f16(af[fi], bf[fj], acc[fi][fj], 0, 0, 0);
    __syncthreads();
  }

  #pragma unroll
  for (int fi = 0; fi < 4; fi++){
    int mb = bm * 128 + wr + fi * 16 + ((lane >> 4) << 2);
    #pragma unroll
    for (int fj = 0; fj < 4; fj++){
      int n = bn * 128 + wc + fj * 16 + lm;
      #pragma unroll
      for (int j = 0; j < 4; j++){
        int m = mb + j;
        if (m < M){
          float v = acc[fi][fj][j];
          size_t o = (size_t)m * N + n;
          if (EPI == 0){
            C[o] = v;
          } else if (EPI == 2){
            Ch[o] = f2h(v);
          } else {
            v += bias[n];
            v = v > 0.0f ? v : 0.2f * v;
            Ch[o] = f2h(v);
          }
        }
      }
    }
  }
}

// ---------------- attention coefficients ----------------

template<int HEADS, int CH, bool HF>
__global__ __launch_bounds__(256) void alpha_kernel(
    const void* __restrict__ Hv, const float* __restrict__ a_s, const float* __restrict__ a_d,
    float* __restrict__ asrc, float* __restrict__ adst, int Nn)
{
  int gw = blockIdx.x * 4 + (threadIdx.x >> 6);
  int lane = threadIdx.x & 63;
  int node = gw / HEADS, hd = gw % HEADS;
  if (node >= Nn) return;
  size_t base = (size_t)node * HEADS * CH + hd * CH;
  const float* asp = a_s + hd * CH;
  const float* adp = a_d + hd * CH;
  float s1 = 0.0f, s2 = 0.0f;
  #pragma unroll
  for (int i = 0; i < CH / 256; i++){
    int off = i * 256 + lane * 4;
    float h0, h1, h2, h3;
    if (HF){
      union { uint2 u; f16 h[4]; } x;
      x.u = *(const uint2*)((const f16*)Hv + base + off);
      h0 = h2f(x.h[0]); h1 = h2f(x.h[1]); h2 = h2f(x.h[2]); h3 = h2f(x.h[3]);
    } else {
      float4 f = *(const float4*)((const float*)Hv + base + off);
      h0 = f.x; h1 = f.y; h2 = f.z; h3 = f.w;
    }
    float4 s4 = *(const float4*)(asp + off);
    float4 d4 = *(const float4*)(adp + off);
    s1 += h0 * s4.x + h1 * s4.y + h2 * s4.z + h3 * s4.w;
    s2 += h0 * d4.x + h1 * d4.y + h2 * d4.z + h3 * d4.w;
  }
  for (int off = 32; off; off >>= 1){
    s1 += __shfl_xor(s1, off);
    s2 += __shfl_xor(s2, off);
  }
  if (lane == 0){ asrc[gw] = s1; adst[gw] = s2; }
}

template<int HEADS>
__global__ __launch_bounds__(256) void softmax_kernel(
    const int* __restrict__ row_ptr, const int* __restrict__ col,
    const float* __restrict__ asrc, const float* __restrict__ adst,
    float* __restrict__ alpha, int Nn)
{
  int dst = blockIdx.x * 4 + (threadIdx.x >> 6);
  int lane = threadIdx.x & 63;
  if (dst >= Nn) return;
  const int hd = (HEADS == 8) ? (lane & 7) : 0;
  const int el = (HEADS == 8) ? (lane >> 3) : lane;
  const int EPP = 64 / HEADS;
  int s = row_ptr[dst], e = row_ptr[dst + 1];
  float ad = adst[dst * HEADS + hd];
  float m = -1e30f;
  for (int p = s + el; p < e; p += EPP){
    float v = asrc[col[p] * HEADS + hd] + ad;
    v = v > 0.0f ? v : 0.2f * v;
    m = fmaxf(m, v);
  }
  for (int off = HEADS; off < 64; off <<= 1) m = fmaxf(m, __shfl_xor(m, off));
  float sum = 0.0f;
  for (int p = s + el; p < e; p += EPP){
    float v = asrc[col[p] * HEADS + hd] + ad;
    v = v > 0.0f ? v : 0.2f * v;
    sum += __expf(v - m);
  }
  for (int off = HEADS; off < 64; off <<= 1) sum += __shfl_xor(sum, off);
  float inv = 1.0f / (sum + 1e-16f);
  for (int p = s + el; p < e; p += EPP){
    float v = asrc[col[p] * HEADS + hd] + ad;
    v = v > 0.0f ? v : 0.2f * v;
    alpha[p * HEADS + hd] = __expf(v - m) * inv;
  }
}

// ---------------- aggregation ----------------

template<int F, int CH, bool FINAL, bool HF>
__global__ __launch_bounds__(256) void agg_kernel(
    const void* __restrict__ Hv, const float* __restrict__ alpha,
    const int* __restrict__ row_ptr, const int* __restrict__ col,
    const float* __restrict__ bias,
    f16* __restrict__ Oh, float* __restrict__ Ofp)
{
  constexpr int CPT = F / 256;
  constexpr int HEADS = F / CH;
  int dst = blockIdx.x;
  int t = threadIdx.x;
  int c0 = t * CPT;
  int hd = c0 / CH;
  float acc[CPT] = {};
  int s = row_ptr[dst], e = row_ptr[dst + 1];
  for (int p = s; p < e; p++){
    int src = col[p];
    float al = alpha[p * HEADS + hd];
    if (HF){
      const f16* hp = (const f16*)Hv + (size_t)src * F + c0;
      if (CPT == 8){
        union { uint4 u; f16 h[8]; } x;
        x.u = *(const uint4*)hp;
        #pragma unroll
        for (int i = 0; i < 8; i++) acc[i] += al * h2f(x.h[i]);
      } else {
        union { u32 u; f16 h[2]; } x;
        x.u = *(const u32*)hp;
        acc[0] += al * h2f(x.h[0]); acc[1] += al * h2f(x.h[1]);
      }
    } else {
      const float* hp = (const float*)Hv + (size_t)src * F + c0;
      if (CPT == 8){
        float4 a = *(const float4*)hp;
        float4 b = *(const float4*)(hp + 4);
        acc[0] += al * a.x; acc[1] += al * a.y; acc[2] += al * a.z; acc[3] += al * a.w;
        acc[4] += al * b.x; acc[5] += al * b.y; acc[6] += al * b.z; acc[7] += al * b.w;
      } else {
        float2 a = *(const float2*)hp;
        acc[0] += al * a.x; acc[1] += al * a.y;
      }
    }
  }
  #pragma unroll
  for (int i = 0; i < CPT; i++){
    float v = acc[i] + bias[c0 + i];
    v = v > 0.0f ? v : 0.2f * v;
    size_t o = (size_t)dst * F + c0 + i;
    if (FINAL) Ofp[o] = v;
    else       Oh[o]  = f2h(v);
  }
}

// ---------------- launcher ----------------

extern "C" void kernel_launch(void* const* d_in, const int* in_sizes, int n_in,
                              void* d_out, int out_size, void* d_ws, size_t ws_size,
                              hipStream_t stream)
{
  const float* x    = (const float*)d_in[0];
  const int*   ei   = (const int*)d_in[1];
  const float* W_in = (const float*)d_in[2];
  const float* b_in = (const float*)d_in[3];
  const float* W1   = (const float*)d_in[4];
  const float* as1  = (const float*)d_in[5];
  const float* ad1  = (const float*)d_in[6];
  const float* b1   = (const float*)d_in[7];
  const float* W2   = (const float*)d_in[8];
  const float* as2  = (const float*)d_in[9];
  const float* ad2  = (const float*)d_in[10];
  const float* b2   = (const float*)d_in[11];
  const float* W3   = (const float*)d_in[12];
  const float* as3  = (const float*)d_in[13];
  const float* ad3  = (const float*)d_in[14];
  const float* b3   = (const float*)d_in[15];

  const int N  = in_sizes[0] / 32;   // 10000
  const int E  = in_sizes[1] / 2;    // 80000
  const int ET = E + N;

  char* w = (char*)d_ws;
  size_t off = 0;
  auto carve = [&](size_t bytes) -> char* {
    off = (off + 255) & ~(size_t)255;
    char* p = w + off;
    off += bytes;
    return p;
  };

  int* flag    = (int*)carve(4);
  int* cnt     = (int*)carve((size_t)N * 4);
  int* fillpos = (int*)carve((size_t)N * 4);
  int* row_ptr = (int*)carve((size_t)(N + 1) * 4);
  int* col     = (int*)carve((size_t)ET * 4);
  f16* xh      = (f16*)carve((size_t)N * 32 * 2);
  f16* h0      = (f16*)carve((size_t)N * 128 * 2);
  f16* WT      = (f16*)carve((size_t)2048 * 2048 * 2);
  f16* Hb      = (f16*)carve((size_t)N * 2048 * 2);   // fp16 h for layers 1,2
  float* H3    = (float*)carve((size_t)N * 512 * 4);  // fp32 h for layer 3
  f16* XB      = (f16*)carve((size_t)N * 2048 * 2);
  float* asrc  = (float*)carve((size_t)N * 8 * 4);
  float* adst  = (float*)carve((size_t)N * 8 * 4);
  float* alpha = (float*)carve((size_t)ET * 8 * 4);

  if (off > ws_size) return;

  const int MT = (N + 127) / 128;   // 79 row-tiles
  float* out = (float*)d_out;

  // CSR build
  detect_kernel<<<1, 1, 0, stream>>>(ei, flag);
  init_kernel<<<(N + 255) / 256, 256, 0, stream>>>(cnt, fillpos, N);
  count_edges<<<(E + 255) / 256, 256, 0, stream>>>(ei, E, flag, cnt);
  scan_kernel<<<1, SCAN_T, 0, stream>>>(cnt, row_ptr, N);
  selfloop_kernel<<<(N + 255) / 256, 256, 0, stream>>>(row_ptr, col, N);
  fill_edges<<<(E + 255) / 256, 256, 0, stream>>>(ei, E, flag, row_ptr, fillpos, col);

  // input projection: h0 = lrelu(x @ W_in + b_in) -> fp16
  convert_f16<<<((long)N * 32 + 255) / 256, 256, 0, stream>>>(x, xh, (long)N * 32);
  convert_wT<<<dim3(1, 4), dim3(32, 8), 0, stream>>>(W_in, WT, 32, 128);
  gemm_kernel<1><<<MT * 1, 256, 0, stream>>>(xh, WT, nullptr, h0, b_in, N, 128, 32, MT, 1);

  // ---- GAT layer 1: 128 -> 8x256 ----
  convert_wT<<<dim3(4, 64), dim3(32, 8), 0, stream>>>(W1, WT, 128, 2048);
  gemm_kernel<2><<<MT * 16, 256, 0, stream>>>(h0, WT, nullptr, Hb, nullptr, N, 2048, 128, MT, 16);
  alpha_kernel<8, 256, true><<<(N * 8 + 3) / 4, 256, 0, stream>>>(Hb, as1, ad1, asrc, adst, N);
  softmax_kernel<8><<<(N + 3) / 4, 256, 0, stream>>>(row_ptr, col, asrc, adst, alpha, N);
  agg_kernel<2048, 256, false, true><<<N, 256, 0, stream>>>(Hb, alpha, row_ptr, col, b1,
      XB, nullptr);

  // ---- GAT layer 2: 2048 -> 8x256 ----
  convert_wT<<<dim3(64, 64), dim3(32, 8), 0, stream>>>(W2, WT, 2048, 2048);
  gemm_kernel<2><<<MT * 16, 256, 0, stream>>>(XB, WT, nullptr, Hb, nullptr, N, 2048, 2048, MT, 16);
  alpha_kernel<8, 256, true><<<(N * 8 + 3) / 4, 256, 0, stream>>>(Hb, as2, ad2, asrc, adst, N);
  softmax_kernel<8><<<(N + 3) / 4, 256, 0, stream>>>(row_ptr, col, asrc, adst, alpha, N);
  agg_kernel<2048, 256, false, true><<<N, 256, 0, stream>>>(Hb, alpha, row_ptr, col, b2,
      XB, nullptr);

  // ---- GAT layer 3: 2048 -> 1x512 (fp32 h to protect final accuracy) ----
  convert_wT<<<dim3(64, 16), dim3(32, 8), 0, stream>>>(W3, WT, 2048, 512);
  gemm_kernel<0><<<MT * 4, 256, 0, stream>>>(XB, WT, H3, nullptr, nullptr, N, 512, 2048, MT, 4);
  alpha_kernel<1, 512, false><<<(N + 3) / 4, 256, 0, stream>>>(H3, as3, ad3, asrc, adst, N);
  softmax_kernel<1><<<(N + 3) / 4, 256, 0, stream>>>(row_ptr, col, asrc, adst, alpha, N);
  agg_kernel<512, 512, true, false><<<N, 256, 0, stream>>>(H3, alpha, row_ptr, col, b3,
      nullptr, out);
}